// Round 8
// baseline (838.960 us; speedup 1.0000x reference)
//
#include <hip/hip_runtime.h>
#include <cstdint>

// Problem constants (MicroCortexMLA): B=2, S=2048, H=2048, NH=16,
// NOPE=128, ROPE=64, VD=128, QLORA=1536, KVLORA=512, theta=1e6, eps=1e-6
// Harness dtypes: fp32 inputs (converted to bf16 in ws), int32 pos, fp32 out.
#define S_LEN 2048
#define NH_N  16
#define VT_LD 2080  // padded row stride for VT_g

typedef short s16x8 __attribute__((ext_vector_type(8)));
typedef unsigned short u16x8 __attribute__((ext_vector_type(8)));
typedef float f32x4 __attribute__((ext_vector_type(4)));

__device__ __forceinline__ float b2f(unsigned short u) {
    return __uint_as_float(((uint32_t)u) << 16);
}
// round-to-nearest-even f32 -> bf16
__device__ __forceinline__ unsigned short f2b(float f) {
    uint32_t x = __float_as_uint(f);
    x += 0x7fffu + ((x >> 16) & 1u);
    return (unsigned short)(x >> 16);
}

__device__ __forceinline__ void cstore(unsigned short* p, float v) { *p = f2b(v); }
__device__ __forceinline__ void cstore(float* p, float v) { *p = v; }

// async global->LDS DMA, 16B per lane. LDS dst is wave-uniform base; HW adds
// lane*16. Tracked by vmcnt; __syncthreads() drains it.
__device__ __forceinline__ void gl2lds16(const void* g, void* l) {
    __builtin_amdgcn_global_load_lds(
        (const __attribute__((address_space(1))) unsigned int*)g,
        (__attribute__((address_space(3))) unsigned int*)l, 16, 0, 0);
}

// lgkm-only barrier: makes LDS writes visible block-wide WITHOUT draining
// vmcnt (in-flight global_load_lds prefetch stays outstanding).
__device__ __forceinline__ void lds_barrier() {
    asm volatile("s_waitcnt lgkmcnt(0)" ::: "memory");
    __builtin_amdgcn_s_barrier();
    __builtin_amdgcn_sched_barrier(0);
}

// ---------------------------------------------------------------------------
// fp32 -> bf16 conversion, vectorized x4, grid-stride. n % 4 == 0.
// ---------------------------------------------------------------------------
__global__ __launch_bounds__(256) void f32_to_bf16(const float* __restrict__ in,
                                                   unsigned short* __restrict__ out,
                                                   long n)
{
    const long nv = n >> 2;
    long i = (long)blockIdx.x * blockDim.x + threadIdx.x;
    const long stride = (long)gridDim.x * blockDim.x;
    for (; i < nv; i += stride) {
        float4 v = ((const float4*)in)[i];
        ushort4 o;
        o.x = f2b(v.x); o.y = f2b(v.y); o.z = f2b(v.z); o.w = f2b(v.w);
        ((ushort4*)out)[i] = o;
    }
}

// ---------------------------------------------------------------------------
// C = A @ B^T, m97-style: 128x128 block tile, BK=32, LDS staged via
// global_load_lds (16B/lane), 2-barrier K-loop. block 256 = 4 waves; wave w
// computes 64x64 at (w>>1, w&1) quadrant = 4x4 MFMA accs.
// LDS granule swizzle: position gp of row holds source granule
// gp ^ ((row ^ (row>>2)) & 3)  -> frag ds_read_b128 2-way max (free).
// Stores guarded by col < Nlim (B rows beyond N read adjacent ws, harmless).
// Batched over blockIdx.z = b*16+h. M%128==0, K%32==0, 16B alignment.
// ---------------------------------------------------------------------------
template <typename CT>
__global__ __launch_bounds__(256) void gemm128(
    const unsigned short* __restrict__ A, const unsigned short* __restrict__ B,
    CT* __restrict__ C,
    int K, int lda, int ldb, int ldc, int Nlim,
    long sAb, long sAh, long sBb, long sBh, long sCb, long sCh)
{
    __shared__ unsigned short Alds[128 * 32];
    __shared__ unsigned short Blds[128 * 32];
    const int z = blockIdx.z, b = z >> 4, h = z & 15;
    A += (long)b * sAb + (long)h * sAh;
    B += (long)b * sBb + (long)h * sBh;
    C += (long)b * sCb + (long)h * sCh;
    const int tid = threadIdx.x;
    const int lane = tid & 63, w = tid >> 6;
    const int l15 = lane & 15, q4 = lane >> 4;
    const int m0 = blockIdx.x * 128, n0 = blockIdx.y * 128;
    const int wm = (w >> 1) * 64, wn = (w & 1) * 64;

    // per-thread staging constants (2 granules per tile)
    int srow[2], sgc[2];
#pragma unroll
    for (int it = 0; it < 2; ++it) {
        const int g = it * 256 + tid;
        const int row = g >> 2, gp = g & 3;
        srow[it] = row;
        sgc[it] = gp ^ ((row ^ (row >> 2)) & 3);
    }
    // per-thread frag read offsets
    int aoff[4], boff[4];
#pragma unroll
    for (int i = 0; i < 4; ++i) {
        const int ra = wm + i * 16 + l15;
        aoff[i] = ra * 32 + (q4 ^ ((ra ^ (ra >> 2)) & 3)) * 8;
        const int rb = wn + i * 16 + l15;
        boff[i] = rb * 32 + (q4 ^ ((rb ^ (rb >> 2)) & 3)) * 8;
    }

    f32x4 acc[4][4];
#pragma unroll
    for (int i = 0; i < 4; ++i)
#pragma unroll
        for (int j = 0; j < 4; ++j) acc[i][j] = (f32x4){0.f, 0.f, 0.f, 0.f};

    for (int k0 = 0; k0 < K; k0 += 32) {
        __syncthreads();  // previous iter's frag reads done
#pragma unroll
        for (int it = 0; it < 2; ++it) {
            gl2lds16(A + (long)(m0 + srow[it]) * lda + k0 + sgc[it] * 8,
                     (char*)Alds + ((it * 256 + w * 64) << 4));
            gl2lds16(B + (long)(n0 + srow[it]) * ldb + k0 + sgc[it] * 8,
                     (char*)Blds + ((it * 256 + w * 64) << 4));
        }
        __syncthreads();  // drain DMA
        s16x8 af[4], bf[4];
#pragma unroll
        for (int i = 0; i < 4; ++i) {
            af[i] = *(const s16x8*)(Alds + aoff[i]);
            bf[i] = *(const s16x8*)(Blds + boff[i]);
        }
#pragma unroll
        for (int i = 0; i < 4; ++i)
#pragma unroll
            for (int j = 0; j < 4; ++j)
                acc[i][j] = __builtin_amdgcn_mfma_f32_16x16x32_bf16(af[i], bf[j], acc[i][j], 0, 0, 0);
    }

#pragma unroll
    for (int i = 0; i < 4; ++i) {
        const int row0 = m0 + wm + i * 16 + q4 * 4;
#pragma unroll
        for (int j = 0; j < 4; ++j) {
            const int col = n0 + wn + j * 16 + l15;
            if (col < Nlim) {
#pragma unroll
                for (int r = 0; r < 4; ++r)
                    cstore(&C[(long)(row0 + r) * ldc + col], acc[i][j][r]);
            }
        }
    }
}

// ---------------------------------------------------------------------------
// In-place RMSNorm over rows of 1536, one block per row.
// ---------------------------------------------------------------------------
__global__ __launch_bounds__(256) void rmsnorm_k(unsigned short* __restrict__ ql,
                                                 const unsigned short* __restrict__ w)
{
    const long base = (long)blockIdx.x * 1536;
    const int tid = threadIdx.x;
    float v[6];
    float ss = 0.f;
#pragma unroll
    for (int i = 0; i < 6; ++i) {
        v[i] = b2f(ql[base + tid + i * 256]);
        ss += v[i] * v[i];
    }
#pragma unroll
    for (int off = 32; off; off >>= 1) ss += __shfl_xor(ss, off, 64);
    __shared__ float red[4];
    if ((tid & 63) == 0) red[tid >> 6] = ss;
    __syncthreads();
    const float tot = red[0] + red[1] + red[2] + red[3];
    const float r = rsqrtf(tot * (1.0f / 1536.0f) + 1e-6f);
#pragma unroll
    for (int i = 0; i < 6; ++i) {
        const int idx = tid + i * 256;
        ql[base + idx] = f2b(v[i] * r * b2f(w[idx]));
    }
}

// ---------------------------------------------------------------------------
// RoPE for q (per head) and k (reference's permuted layout, consistent q/k).
// ---------------------------------------------------------------------------
__global__ __launch_bounds__(512) void rope_k(
    const unsigned short* __restrict__ q, const unsigned short* __restrict__ ckv,
    const int* __restrict__ pos_ids,
    unsigned short* __restrict__ q_rope, unsigned short* __restrict__ krope)
{
    const int bs = blockIdx.x;
    const int b = bs >> 11, s = bs & 2047;
    const int t = threadIdx.x;
    const int j = t & 31, h = t >> 5;
    const float pos = (float)pos_ids[bs];
    const float invf = __expf(-(float)j * 0.4317347f);  // ln(1e6)/32
    float sn, cs;
    sincosf(pos * invf, &sn, &cs);
    const unsigned short* x = q + (long)bs * 3072 + h * 192 + 128;
    const float x0 = b2f(x[2 * j]), x1 = b2f(x[2 * j + 1]);
    const long ob = ((long)(b * NH_N + h) * S_LEN + s) * 64;
    q_rope[ob + j]      = f2b(x0 * cs - x1 * sn);
    q_rope[ob + 32 + j] = f2b(x1 * cs + x0 * sn);
    if (h == 0) {
        const unsigned short* y = ckv + (long)bs * 576 + 512;
        const float y0 = b2f(y[2 * j]), y1 = b2f(y[2 * j + 1]);
        const long ob2 = (long)bs * 64;
        krope[ob2 + j]      = f2b(y0 * cs - y1 * sn);
        krope[ob2 + 32 + j] = f2b(y1 * cs + y0 * sn);
    }
}

// qT[h][c][n] = Wkv_up[(h*256+n)*512 + c]
__global__ __launch_bounds__(256) void transpose_qabsorb(
    const unsigned short* __restrict__ Wkv_up, unsigned short* __restrict__ qT)
{
    const int idx = blockIdx.x * 256 + threadIdx.x;
    const int n = idx & 127;
    const int c = (idx >> 7) & 511;
    const int h = idx >> 16;
    qT[idx] = Wkv_up[((long)(h * 256 + n)) * 512 + c];
}

// ---------------------------------------------------------------------------
// VT_g[b][c][key] = ckv[b][key][c]  (c < 512) — V^T for the PV MFMA B-frags.
// Tiled 64x64 transpose through LDS. grid (32 keyblk, 8 cblk, 2 b).
// ---------------------------------------------------------------------------
__global__ __launch_bounds__(256) void transpose_ckv(
    const unsigned short* __restrict__ ckv, unsigned short* __restrict__ VT_g)
{
    __shared__ unsigned short t[64][72];  // +8 pad
    const int k0 = blockIdx.x * 64, c0 = blockIdx.y * 64, b = blockIdx.z;
    const int tid = threadIdx.x;
#pragma unroll
    for (int it = 0; it < 2; ++it) {
        int idx = tid + it * 256;  // 512 tasks: 64 rows x 8 granules
        int row = idx >> 3, g = idx & 7;
        *(s16x8*)&t[row][g * 8] =
            *(const s16x8*)(ckv + ((long)(b * S_LEN + k0 + row) * 576 + c0 + g * 8));
    }
    __syncthreads();
#pragma unroll
    for (int it = 0; it < 2; ++it) {
        int idx = tid + it * 256;  // 512 tasks: 64 c x 8 key-granules
        int c = idx >> 3, g = idx & 7;
        u16x8 v;
#pragma unroll
        for (int j = 0; j < 8; ++j) v[j] = t[g * 8 + j][c];
        *(u16x8*)(VT_g + ((long)(b * 512 + c0 + c) * VT_LD + k0 + g * 8)) = v;
    }
}

// ---------------------------------------------------------------------------
// MFMA flash attention in the 576-dim latent space (512 c + 64 rope).
// v8 = v7 with the MID-TILE BARRIER REMOVED via lagged PV:
//   v7 post-mortem: not LDS-throughput-bound (v2 13.9k -> v7 12.8k cyc/tile
//   despite -30% LDS traffic; LDS~5k + MFMA~2.6k + VALU~2.4k << 12.8k wall).
//   The wall is PHASE ALIGNMENT: 2 barriers/tile force all 8 waves into
//   lockstep bursts (K-read burst -> softmax burst -> PV burst; pipes idle
//   in turn). Fix: per iteration run S(kt) || PV(kt-1) as independent
//   streams with ONE end-of-tile barrier:
//   - P/alpha/flag double-buffered (S writes [kt&1]; PV reads [(kt-1)&1],
//     published by the previous barrier).
//   - V SINGLE-buffered with per-wave self-staging: c-split means wave w
//     only ever touches its own 4KB c-slice; it reads its V(kt-1) frags to
//     regs, waits own lgkmcnt, then stages V(kt) over its own slice (DMA
//     latency >> LDS-read latency; no cross-wave access to the slice).
//   - epilogue PV consumes the last tile's P after the loop.
//   LDS: K dbuf 72K + V 32K + P dbuf 20K + misc ~= 128.5 KB (1 block/CU).
//
// grid (32 bh, 8 y); block 512 = 8 waves; q-tiles qt=15-y then y => exactly
// 68 key-tiles/block. Staging maps, softmax (log2-domain, defer-max THR=8,
// per-lane l partials), causal masks, c-split PV and guards are byte-
// identical to the verified v7 (just with lagged k0' = k0-32 on the PV side).
// ---------------------------------------------------------------------------
__global__ __launch_bounds__(512, 1) void flash_mfma(
    const unsigned short* __restrict__ qabs,  const unsigned short* __restrict__ qrope,
    const unsigned short* __restrict__ ckv,   const unsigned short* __restrict__ krope,
    const unsigned short* __restrict__ VT_g,  unsigned short* __restrict__ attn_out)
{
    __shared__ unsigned short K_lds[2][2304 * 8];       // 2 x 36 KB
    __shared__ unsigned short V_lds[2048 * 8];          // 32 KB, per-wave slices
    __shared__ unsigned short P_lds[2][8][16 * 40];     // dbuf, +8 pad rows
    __shared__ __align__(16) float alpha_lds[2][8 * 16];
    __shared__ __align__(16) float inv_lds[8 * 16];
    __shared__ int flag_lds[2][8];

    const float scale2 = 0.10412195f;   // (1/sqrt(192)) * log2(e)
    const float THR    = 11.5416f;      // 8 * log2(e)
    const int tid = threadIdx.x;
    const int lane = tid & 63, w = tid >> 6;
    const int l15 = lane & 15, q4 = lane >> 4;
    const int bh = blockIdx.x;
    const int b = bh >> 4;

    const unsigned short* ckv_b  = ckv   + (long)b * S_LEN * 576;
    const unsigned short* krop_b = krope + (long)b * S_LEN * 64;
    const unsigned short* vt_b   = VT_g  + (long)b * 512 * VT_LD;

    // K staging source offsets (bf16 elements), v7 mapping
    int koff[4];
#pragma unroll
    for (int it = 0; it < 4; ++it) {
        const int idx = it * 512 + tid;
        const int key = ((idx >> 6) & 1) * 16 + (idx & 15);
        const int g   = (idx >> 7) * 4 + ((idx >> 4) & 3);   // < 64
        koff[it] = key * 576 + g * 8;
    }
    const int hoff = (((tid >> 6) & 1) * 16 + (tid & 15)) * 64 +
                     ((tid >> 7) * 4 + ((tid >> 4) & 3)) * 8;   // krope (tid<256)

    // V self-staging source offsets: wave w stages granules [w*256, w*256+256)
    // (its own c-slice). granule g -> c = (g>>6)*16 + (g&15), key-slot (g>>4)&3;
    // for instr i, g = w*256 + i*64 + lane -> c = (w*4+i)*16 + l15, slot = q4.
    long vsoff[4];
#pragma unroll
    for (int i = 0; i < 4; ++i)
        vsoff[i] = (long)((w * 4 + i) * 16 + l15) * VT_LD + q4 * 8;

#pragma unroll 1
    for (int half = 0; half < 2; ++half) {
        const int qt = half ? blockIdx.y : 15 - blockIdx.y;
        const int q0 = qt * 128;

        // Q fragments: rows q0 + w*16 + l15, dims kb*32 + q4*8 (+j)
        s16x8 qf[18];
        {
            const unsigned short* qa = qabs + ((long)bh * S_LEN + q0 + w * 16 + l15) * 512 + q4 * 8;
#pragma unroll
            for (int kb = 0; kb < 16; ++kb) qf[kb] = *(const s16x8*)(qa + kb * 32);
            const unsigned short* qr = qrope + ((long)bh * S_LEN + q0 + w * 16 + l15) * 64 + q4 * 8;
            qf[16] = *(const s16x8*)(qr);
            qf[17] = *(const s16x8*)(qr + 32);
        }

        // O[rb][cb]: 16 rows (rowblock rb) x 16 c (c = w*64 + cb*16 + l15)
        f32x4 O[32];
#pragma unroll
        for (int i = 0; i < 32; ++i) O[i] = (f32x4){0.f, 0.f, 0.f, 0.f};
        float m_i[4] = {-INFINITY, -INFINITY, -INFINITY, -INFINITY};
        float l_i[4] = {0.f, 0.f, 0.f, 0.f};

        const int nkt = 4 * qt + 4;
        unsigned short *Kc = K_lds[0], *Kn = K_lds[1];

        // ---- prologue: stage K tile 0 ----
        {
#pragma unroll
            for (int it = 0; it < 4; ++it)
                gl2lds16(ckv_b + koff[it], (char*)Kc + ((it * 512 + w * 64) << 4));
            if (tid < 256)
                gl2lds16(krop_b + hoff, (char*)Kc + ((2048 + w * 64) << 4));
        }
        __syncthreads();  // drain tile-0 K DMA

// rescale-O + PV for tile with key-base K0P from P/alpha/flag buffer PRV,
// V frags in VH (wave's own c-slice). rb-activity guard matches S at K0P.
#define PV_TILE(PRV, K0P, VH)                                                              \
        {                                                                                  \
            const int* fp = flag_lds[PRV];                                                 \
            const int anyf = fp[0] | fp[1] | fp[2] | fp[3] | fp[4] | fp[5] | fp[6] | fp[7];\
            if (anyf) {                                                                    \
                _Pragma("unroll")                                                          \
                for (int rb = 0; rb < 8; ++rb) {                                           \
                    if ((K0P) <= q0 + rb * 16 + 15) {                                      \
                        f32x4 alr = *(const f32x4*)&alpha_lds[PRV][rb * 16 + q4 * 4];      \
                        _Pragma("unroll")                                                  \
                        for (int cb = 0; cb < 4; ++cb)                                     \
                            _Pragma("unroll")                                              \
                            for (int r = 0; r < 4; ++r)                                    \
                                O[rb * 4 + cb][r] *= alr[r];                               \
                    }                                                                      \
                }                                                                          \
            }                                                                              \
            _Pragma("unroll")                                                              \
            for (int rb = 0; rb < 8; ++rb) {                                               \
                if ((K0P) <= q0 + rb * 16 + 15) {                                          \
                    s16x8 pa = *(const s16x8*)&P_lds[PRV][rb][l15 * 40 + q4 * 8];          \
                    __builtin_amdgcn_s_setprio(1);                                         \
                    _Pragma("unroll")                                                      \
                    for (int cb = 0; cb < 4; ++cb)                                         \
                        O[rb * 4 + cb] = __builtin_amdgcn_mfma_f32_16x16x32_bf16(          \
                            pa, VH[cb], O[rb * 4 + cb], 0, 0, 0);                          \
                    __builtin_amdgcn_s_setprio(0);                                         \
                }                                                                          \
            }                                                                              \
        }

        for (int kt = 0; kt < nkt; ++kt) {
            const int k0 = kt * 32;
            const int cur = kt & 1, prv = cur ^ 1;
            const int k0p = k0 - 32;

            // ---- stage K tile kt+1 (lands under this tile's compute) ----
            if (kt + 1 < nkt) {
                const int kn = k0 + 32;
                const unsigned short* cs = ckv_b + (long)kn * 576;
#pragma unroll
                for (int it = 0; it < 4; ++it)
                    gl2lds16(cs + koff[it], (char*)Kn + ((it * 512 + w * 64) << 4));
                if (tid < 256)
                    gl2lds16(krop_b + (long)kn * 64 + hoff, (char*)Kn + ((2048 + w * 64) << 4));
            }

            // ---- V: read my V(kt-1) frags, then self-stage V(kt) over my
            //      own slice (own-lgkm wait orders read-before-overwrite) ----
            s16x8 vh[4];
            if (kt > 0) {
#pragma unroll
                for (int cb = 0; cb < 4; ++cb)
                    vh[cb] = *(const s16x8*)&V_lds[((w * 4 + cb) * 64 + lane) * 8];
            }
            asm volatile("s_waitcnt lgkmcnt(0)" ::: "memory");
#pragma unroll
            for (int i = 0; i < 4; ++i)
                gl2lds16(vt_b + vsoff[i] + k0, (char*)V_lds + ((w * 256 + i * 64) << 4));

            // ---- S(kt) for MY 16 rows (skip if fully masked) ----
            if (k0 <= q0 + (w << 4) + 15) {
                f32x4 s0 = {0.f, 0.f, 0.f, 0.f}, s1 = s0;
                __builtin_amdgcn_s_setprio(1);
#pragma unroll
                for (int kb = 0; kb < 18; ++kb) {
                    s16x8 k0f = *(const s16x8*)&Kc[((kb * 2 + 0) * 64 + lane) * 8];
                    s16x8 k1f = *(const s16x8*)&Kc[((kb * 2 + 1) * 64 + lane) * 8];
                    s0 = __builtin_amdgcn_mfma_f32_16x16x32_bf16(qf[kb], k0f, s0, 0, 0, 0);
                    s1 = __builtin_amdgcn_mfma_f32_16x16x32_bf16(qf[kb], k1f, s1, 0, 0, 0);
                }
                __builtin_amdgcn_s_setprio(0);
#pragma unroll
                for (int r = 0; r < 4; ++r) { s0[r] *= scale2; s1[r] *= scale2; }
                if (k0 + 31 > q0 + (w << 4)) {  // diagonal tiles: causal mask
#pragma unroll
                    for (int r = 0; r < 4; ++r) {
                        const int qg = q0 + w * 16 + q4 * 4 + r;
                        if (k0 + l15 > qg)      s0[r] = -INFINITY;
                        if (k0 + 16 + l15 > qg) s1[r] = -INFINITY;
                    }
                }

                // online softmax (log2 domain, defer-max)
                float mx[4];
#pragma unroll
                for (int r = 0; r < 4; ++r) {
                    float m = fmaxf(s0[r], s1[r]);
#pragma unroll
                    for (int off = 1; off < 16; off <<= 1) m = fmaxf(m, __shfl_xor(m, off, 64));
                    mx[r] = m;   // uniform within the 16-lane row group
                }
                bool need = false;
#pragma unroll
                for (int r = 0; r < 4; ++r) need = need || (mx[r] - m_i[r] > THR);
                const bool needw = __any(need);
                float al[4] = {1.f, 1.f, 1.f, 1.f};
                if (needw) {
#pragma unroll
                    for (int r = 0; r < 4; ++r) {
                        const float mn = fmaxf(m_i[r], mx[r]);
                        al[r] = exp2f(m_i[r] - mn);   // first tile: exp2(-inf)=0
                        m_i[r] = mn;
                        l_i[r] *= al[r];
                    }
                }
                if (l15 == 0)
                    *(f32x4*)&alpha_lds[cur][w * 16 + q4 * 4] = (f32x4){al[0], al[1], al[2], al[3]};
                if (lane == 0) flag_lds[cur][w] = needw ? 1 : 0;
#pragma unroll
                for (int r = 0; r < 4; ++r) {
                    const float p0 = exp2f(s0[r] - m_i[r]);
                    const float p1 = exp2f(s1[r] - m_i[r]);
                    l_i[r] += p0 + p1;   // per-lane partial; reduced in epilogue
                    P_lds[cur][w][(q4 * 4 + r) * 40 + l15]      = f2b(p0);
                    P_lds[cur][w][(q4 * 4 + r) * 40 + 16 + l15] = f2b(p1);
                }
            } else {
                if (lane == 0) flag_lds[cur][w] = 0;
            }

            // ---- PV(kt-1): independent of S(kt) -> scheduler/waves overlap ----
            if (kt > 0) {
                PV_TILE(prv, k0p, vh)
            }

            // ---- ONE barrier per tile: drains K(kt+1)+V(kt) DMA, publishes
            //      P/alpha/flag(kt), protects buffer swap ----
            __syncthreads();
            unsigned short* t;
            t = Kc; Kc = Kn; Kn = t;
        }

        // ---- epilogue PV for the last tile ----
        {
            const int prv = (nkt - 1) & 1;
            const int k0p = (nkt - 1) * 32;
            s16x8 vh[4];
#pragma unroll
            for (int cb = 0; cb < 4; ++cb)
                vh[cb] = *(const s16x8*)&V_lds[((w * 4 + cb) * 64 + lane) * 8];
            PV_TILE(prv, k0p, vh)
        }
#undef PV_TILE

        // ---- epilogue: per-row 1/l via LDS, O *= inv, c-split store ----
#pragma unroll
        for (int r = 0; r < 4; ++r) {
            float ls = l_i[r];
#pragma unroll
            for (int off = 1; off < 16; off <<= 1) ls += __shfl_xor(ls, off, 64);
            l_i[r] = 1.0f / ls;
        }
        if (l15 == 0)
            *(f32x4*)&inv_lds[w * 16 + q4 * 4] = (f32x4){l_i[0], l_i[1], l_i[2], l_i[3]};
        lds_barrier();
#pragma unroll
        for (int rb = 0; rb < 8; ++rb) {
            f32x4 ivr = *(const f32x4*)&inv_lds[rb * 16 + q4 * 4];
#pragma unroll
            for (int r = 0; r < 4; ++r) {
                const long rowbase = ((long)bh * S_LEN + q0 + rb * 16 + q4 * 4 + r) * 512;
#pragma unroll
                for (int cb = 0; cb < 4; ++cb)
                    attn_out[rowbase + w * 64 + cb * 16 + l15] = f2b(O[rb * 4 + cb][r] * ivr[r]);
            }
        }
        __syncthreads();  // P/alpha/V/inv reuse guard for next half
    }
}

// ---------------------------------------------------------------------------
extern "C" void kernel_launch(void* const* d_in, const int* in_sizes, int n_in,
                              void* d_out, int out_size, void* d_ws, size_t ws_size,
                              hipStream_t stream)
{
    (void)in_sizes; (void)n_in; (void)out_size; (void)ws_size;
    const float* hs_f       = (const float*)d_in[0];
    const int*   pos        = (const int*)d_in[1];
    // d_in[2] = attention_mask (causal, recomputed analytically) - unused
    const float* Wq_down_f  = (const float*)d_in[3];
    const float* q_ln_w_f   = (const float*)d_in[4];
    const float* Wq_up_f    = (const float*)d_in[5];
    const float* Wkv_down_f = (const float*)d_in[6];
    const float* Wkv_up_f   = (const float*)d_in[7];
    const float* Wo_f       = (const float*)d_in[8];
    float* out = (float*)d_out;

    // workspace layout (bf16 elements). out2 aliases q (dead after step 7).
    unsigned short* ws    = (unsigned short*)d_ws;
    unsigned short* ql    = ws;                        // 4096*1536
    unsigned short* q     = ql    + 4096L * 1536;      // 4096*3072
    unsigned short* out2  = q;                         // 4096*2048 (alias)
    unsigned short* ckv   = q     + 4096L * 3072;      // 4096*576
    unsigned short* krope = ckv   + 4096L * 576;       // 4096*64
    unsigned short* qrope = krope + 4096L * 64;        // 32*2048*64
    unsigned short* qabsT = qrope + 32L * 2048 * 64;   // 16*512*128
    unsigned short* qabs  = qabsT + 16L * 512 * 128;   // 32*2048*512
    unsigned short* attno = qabs  + 32L * 2048 * 512;  // 32*2048*512
    unsigned short* hs    = attno + 32L * 2048 * 512;  // 4096*2048
    unsigned short* Wqd   = hs    + 4096L * 2048;      // 1536*2048
    unsigned short* qlnw  = Wqd   + 1536L * 2048;      // 1536
    unsigned short* Wqu   = qlnw  + 1536;              // 3072*1536
    unsigned short* Wkvd  = Wqu   + 3072L * 1536;      // 576*2048
    unsigned short* Wkvu  = Wkvd  + 576L * 2048;       // 16*256*512
    unsigned short* Wob   = Wkvu  + 16L * 256 * 512;   // 2048*2048
    unsigned short* VTg   = Wob   + 2048L * 2048;      // 2*512*VT_LD (padded)

    // 0) fp32 -> bf16 input conversion
    f32_to_bf16<<<4096, 256, 0, stream>>>(hs_f,       hs,   4096L * 2048);
    f32_to_bf16<<<3072, 256, 0, stream>>>(Wq_down_f,  Wqd,  1536L * 2048);
    f32_to_bf16<<<2,    256, 0, stream>>>(q_ln_w_f,   qlnw, 1536L);
    f32_to_bf16<<<4096, 256, 0, stream>>>(Wq_up_f,    Wqu,  3072L * 1536);
    f32_to_bf16<<<1152, 256, 0, stream>>>(Wkv_down_f, Wkvd, 576L * 2048);
    f32_to_bf16<<<2048, 256, 0, stream>>>(Wkv_up_f,   Wkvu, 16L * 256 * 512);
    f32_to_bf16<<<4096, 256, 0, stream>>>(Wo_f,       Wob,  2048L * 2048);

    // 1) ql = hs @ Wq_down^T   (4096x1536, K=2048)
    gemm128<unsigned short><<<dim3(32, 12, 1), 256, 0, stream>>>(hs, Wqd, ql,
        2048, 2048, 2048, 1536, 1536, 0, 0, 0, 0, 0, 0);
    // 2) RMSNorm(ql)
    rmsnorm_k<<<4096, 256, 0, stream>>>(ql, qlnw);
    // 3) q = ql @ Wq_up^T      (4096x3072, K=1536)
    gemm128<unsigned short><<<dim3(32, 24, 1), 256, 0, stream>>>(ql, Wqu, q,
        1536, 1536, 1536, 3072, 3072, 0, 0, 0, 0, 0, 0);
    // 4) ckv = hs @ Wkv_down^T (2048x576, K=2048); Nlim guards last tile
    gemm128<unsigned short><<<dim3(32, 5, 1), 256, 0, stream>>>(hs, Wkvd, ckv,
        2048, 2048, 2048, 576, 576, 0, 0, 0, 0, 0, 0);
    // 5) RoPE on q (per head) and k
    rope_k<<<4096, 512, 0, stream>>>(q, ckv, pos, qrope, krope);
    // 5b) VT_g[b][c][key] = ckv[b][key][c], row stride VT_LD
    transpose_ckv<<<dim3(32, 8, 2), 256, 0, stream>>>(ckv, VTg);
    // 6) transpose q_absorb -> (h, c, n)
    transpose_qabsorb<<<4096, 256, 0, stream>>>(Wkvu, qabsT);
    // 7) q_abs[b,h] = q_nope[b,h] @ q_absorbT[h]^T  (2048x512, K=128), batched 32
    gemm128<unsigned short><<<dim3(16, 4, 32), 256, 0, stream>>>(q, qabsT, qabs,
        128, 3072, 128, 512, 512,
        2048L * 3072, 192, 0, 512L * 128, 16L * 2048 * 512, 2048L * 512);
    // 8) MFMA flash attention -> attn_out (B,NH,S,512): single-barrier tile,
    //    S(kt) || PV(kt-1), P dbuf, V per-wave self-staged; 128.5 KB LDS
    flash_mfma<<<dim3(32, 8, 1), 512, 0, stream>>>(qabs, qrope, ckv, krope, VTg, attno);
    // 9) out2 = attn_out @ out_absorb^T per head (2048x128, K=512), batched 32
    gemm128<unsigned short><<<dim3(16, 1, 32), 256, 0, stream>>>(attno, Wkvu + 128L * 512, out2,
        512, 512, 512, 2048, 128,
        16L * 2048 * 512, 2048L * 512, 0, 256L * 512, 2048L * 2048, 128);
    // 10) out = out2 @ Wo^T    (4096x2048, K=2048), fp32 output
    gemm128<float><<<dim3(32, 16, 1), 256, 0, stream>>>(out2, Wob, out,
        2048, 2048, 2048, 2048, 2048, 0, 0, 0, 0, 0, 0);
}

// Round 9
// 785.913 us; speedup vs baseline: 1.0675x; 1.0675x over previous
//
#include <hip/hip_runtime.h>
#include <cstdint>

// Problem constants (MicroCortexMLA): B=2, S=2048, H=2048, NH=16,
// NOPE=128, ROPE=64, VD=128, QLORA=1536, KVLORA=512, theta=1e6, eps=1e-6
// Harness dtypes: fp32 inputs (converted to bf16 in ws), int32 pos, fp32 out.
#define S_LEN 2048
#define NH_N  16
#define VT_LD 2080  // padded row stride for VT_g

typedef short s16x8 __attribute__((ext_vector_type(8)));
typedef unsigned short u16x8 __attribute__((ext_vector_type(8)));
typedef float f32x4 __attribute__((ext_vector_type(4)));

__device__ __forceinline__ float b2f(unsigned short u) {
    return __uint_as_float(((uint32_t)u) << 16);
}
// round-to-nearest-even f32 -> bf16
__device__ __forceinline__ unsigned short f2b(float f) {
    uint32_t x = __float_as_uint(f);
    x += 0x7fffu + ((x >> 16) & 1u);
    return (unsigned short)(x >> 16);
}

__device__ __forceinline__ void cstore(unsigned short* p, float v) { *p = f2b(v); }
__device__ __forceinline__ void cstore(float* p, float v) { *p = v; }

// async global->LDS DMA, 16B per lane. LDS dst is wave-uniform base; HW adds
// lane*16. Tracked by vmcnt; __syncthreads() drains it.
__device__ __forceinline__ void gl2lds16(const void* g, void* l) {
    __builtin_amdgcn_global_load_lds(
        (const __attribute__((address_space(1))) unsigned int*)g,
        (__attribute__((address_space(3))) unsigned int*)l, 16, 0, 0);
}

// lgkm-only barrier: makes LDS writes visible block-wide WITHOUT draining
// vmcnt (in-flight global_load_lds prefetch stays outstanding).
__device__ __forceinline__ void lds_barrier() {
    asm volatile("s_waitcnt lgkmcnt(0)" ::: "memory");
    __builtin_amdgcn_s_barrier();
    __builtin_amdgcn_sched_barrier(0);
}

// ---------------------------------------------------------------------------
// fp32 -> bf16 conversion, vectorized x4, grid-stride. n % 4 == 0.
// ---------------------------------------------------------------------------
__global__ __launch_bounds__(256) void f32_to_bf16(const float* __restrict__ in,
                                                   unsigned short* __restrict__ out,
                                                   long n)
{
    const long nv = n >> 2;
    long i = (long)blockIdx.x * blockDim.x + threadIdx.x;
    const long stride = (long)gridDim.x * blockDim.x;
    for (; i < nv; i += stride) {
        float4 v = ((const float4*)in)[i];
        ushort4 o;
        o.x = f2b(v.x); o.y = f2b(v.y); o.z = f2b(v.z); o.w = f2b(v.w);
        ((ushort4*)out)[i] = o;
    }
}

// ---------------------------------------------------------------------------
// C = A @ B^T, m97-style: 128x128 block tile, BK=32, LDS staged via
// global_load_lds (16B/lane), 2-barrier K-loop. block 256 = 4 waves; wave w
// computes 64x64 at (w>>1, w&1) quadrant = 4x4 MFMA accs.
// LDS granule swizzle: position gp of row holds source granule
// gp ^ ((row ^ (row>>2)) & 3)  -> frag ds_read_b128 2-way max (free).
// Stores guarded by col < Nlim (B rows beyond N read adjacent ws, harmless).
// Batched over blockIdx.z = b*16+h. M%128==0, K%32==0, 16B alignment.
// ---------------------------------------------------------------------------
template <typename CT>
__global__ __launch_bounds__(256) void gemm128(
    const unsigned short* __restrict__ A, const unsigned short* __restrict__ B,
    CT* __restrict__ C,
    int K, int lda, int ldb, int ldc, int Nlim,
    long sAb, long sAh, long sBb, long sBh, long sCb, long sCh)
{
    __shared__ unsigned short Alds[128 * 32];
    __shared__ unsigned short Blds[128 * 32];
    const int z = blockIdx.z, b = z >> 4, h = z & 15;
    A += (long)b * sAb + (long)h * sAh;
    B += (long)b * sBb + (long)h * sBh;
    C += (long)b * sCb + (long)h * sCh;
    const int tid = threadIdx.x;
    const int lane = tid & 63, w = tid >> 6;
    const int l15 = lane & 15, q4 = lane >> 4;
    const int m0 = blockIdx.x * 128, n0 = blockIdx.y * 128;
    const int wm = (w >> 1) * 64, wn = (w & 1) * 64;

    // per-thread staging constants (2 granules per tile)
    int srow[2], sgc[2];
#pragma unroll
    for (int it = 0; it < 2; ++it) {
        const int g = it * 256 + tid;
        const int row = g >> 2, gp = g & 3;
        srow[it] = row;
        sgc[it] = gp ^ ((row ^ (row >> 2)) & 3);
    }
    // per-thread frag read offsets
    int aoff[4], boff[4];
#pragma unroll
    for (int i = 0; i < 4; ++i) {
        const int ra = wm + i * 16 + l15;
        aoff[i] = ra * 32 + (q4 ^ ((ra ^ (ra >> 2)) & 3)) * 8;
        const int rb = wn + i * 16 + l15;
        boff[i] = rb * 32 + (q4 ^ ((rb ^ (rb >> 2)) & 3)) * 8;
    }

    f32x4 acc[4][4];
#pragma unroll
    for (int i = 0; i < 4; ++i)
#pragma unroll
        for (int j = 0; j < 4; ++j) acc[i][j] = (f32x4){0.f, 0.f, 0.f, 0.f};

    for (int k0 = 0; k0 < K; k0 += 32) {
        __syncthreads();  // previous iter's frag reads done
#pragma unroll
        for (int it = 0; it < 2; ++it) {
            gl2lds16(A + (long)(m0 + srow[it]) * lda + k0 + sgc[it] * 8,
                     (char*)Alds + ((it * 256 + w * 64) << 4));
            gl2lds16(B + (long)(n0 + srow[it]) * ldb + k0 + sgc[it] * 8,
                     (char*)Blds + ((it * 256 + w * 64) << 4));
        }
        __syncthreads();  // drain DMA
        s16x8 af[4], bf[4];
#pragma unroll
        for (int i = 0; i < 4; ++i) {
            af[i] = *(const s16x8*)(Alds + aoff[i]);
            bf[i] = *(const s16x8*)(Blds + boff[i]);
        }
#pragma unroll
        for (int i = 0; i < 4; ++i)
#pragma unroll
            for (int j = 0; j < 4; ++j)
                acc[i][j] = __builtin_amdgcn_mfma_f32_16x16x32_bf16(af[i], bf[j], acc[i][j], 0, 0, 0);
    }

#pragma unroll
    for (int i = 0; i < 4; ++i) {
        const int row0 = m0 + wm + i * 16 + q4 * 4;
#pragma unroll
        for (int j = 0; j < 4; ++j) {
            const int col = n0 + wn + j * 16 + l15;
            if (col < Nlim) {
#pragma unroll
                for (int r = 0; r < 4; ++r)
                    cstore(&C[(long)(row0 + r) * ldc + col], acc[i][j][r]);
            }
        }
    }
}

// ---------------------------------------------------------------------------
// In-place RMSNorm over rows of 1536, one block per row.
// ---------------------------------------------------------------------------
__global__ __launch_bounds__(256) void rmsnorm_k(unsigned short* __restrict__ ql,
                                                 const unsigned short* __restrict__ w)
{
    const long base = (long)blockIdx.x * 1536;
    const int tid = threadIdx.x;
    float v[6];
    float ss = 0.f;
#pragma unroll
    for (int i = 0; i < 6; ++i) {
        v[i] = b2f(ql[base + tid + i * 256]);
        ss += v[i] * v[i];
    }
#pragma unroll
    for (int off = 32; off; off >>= 1) ss += __shfl_xor(ss, off, 64);
    __shared__ float red[4];
    if ((tid & 63) == 0) red[tid >> 6] = ss;
    __syncthreads();
    const float tot = red[0] + red[1] + red[2] + red[3];
    const float r = rsqrtf(tot * (1.0f / 1536.0f) + 1e-6f);
#pragma unroll
    for (int i = 0; i < 6; ++i) {
        const int idx = tid + i * 256;
        ql[base + idx] = f2b(v[i] * r * b2f(w[idx]));
    }
}

// ---------------------------------------------------------------------------
// RoPE for q (per head) and k (reference's permuted layout, consistent q/k).
// ---------------------------------------------------------------------------
__global__ __launch_bounds__(512) void rope_k(
    const unsigned short* __restrict__ q, const unsigned short* __restrict__ ckv,
    const int* __restrict__ pos_ids,
    unsigned short* __restrict__ q_rope, unsigned short* __restrict__ krope)
{
    const int bs = blockIdx.x;
    const int b = bs >> 11, s = bs & 2047;
    const int t = threadIdx.x;
    const int j = t & 31, h = t >> 5;
    const float pos = (float)pos_ids[bs];
    const float invf = __expf(-(float)j * 0.4317347f);  // ln(1e6)/32
    float sn, cs;
    sincosf(pos * invf, &sn, &cs);
    const unsigned short* x = q + (long)bs * 3072 + h * 192 + 128;
    const float x0 = b2f(x[2 * j]), x1 = b2f(x[2 * j + 1]);
    const long ob = ((long)(b * NH_N + h) * S_LEN + s) * 64;
    q_rope[ob + j]      = f2b(x0 * cs - x1 * sn);
    q_rope[ob + 32 + j] = f2b(x1 * cs + x0 * sn);
    if (h == 0) {
        const unsigned short* y = ckv + (long)bs * 576 + 512;
        const float y0 = b2f(y[2 * j]), y1 = b2f(y[2 * j + 1]);
        const long ob2 = (long)bs * 64;
        krope[ob2 + j]      = f2b(y0 * cs - y1 * sn);
        krope[ob2 + 32 + j] = f2b(y1 * cs + y0 * sn);
    }
}

// qT[h][c][n] = Wkv_up[(h*256+n)*512 + c]
__global__ __launch_bounds__(256) void transpose_qabsorb(
    const unsigned short* __restrict__ Wkv_up, unsigned short* __restrict__ qT)
{
    const int idx = blockIdx.x * 256 + threadIdx.x;
    const int n = idx & 127;
    const int c = (idx >> 7) & 511;
    const int h = idx >> 16;
    qT[idx] = Wkv_up[((long)(h * 256 + n)) * 512 + c];
}

// ---------------------------------------------------------------------------
// VT_g[b][c][key] = ckv[b][key][c]  (c < 512) — V^T for the PV MFMA B-frags.
// Tiled 64x64 transpose through LDS. grid (32 keyblk, 8 cblk, 2 b).
// ---------------------------------------------------------------------------
__global__ __launch_bounds__(256) void transpose_ckv(
    const unsigned short* __restrict__ ckv, unsigned short* __restrict__ VT_g)
{
    __shared__ unsigned short t[64][72];  // +8 pad
    const int k0 = blockIdx.x * 64, c0 = blockIdx.y * 64, b = blockIdx.z;
    const int tid = threadIdx.x;
#pragma unroll
    for (int it = 0; it < 2; ++it) {
        int idx = tid + it * 256;  // 512 tasks: 64 rows x 8 granules
        int row = idx >> 3, g = idx & 7;
        *(s16x8*)&t[row][g * 8] =
            *(const s16x8*)(ckv + ((long)(b * S_LEN + k0 + row) * 576 + c0 + g * 8));
    }
    __syncthreads();
#pragma unroll
    for (int it = 0; it < 2; ++it) {
        int idx = tid + it * 256;  // 512 tasks: 64 c x 8 key-granules
        int c = idx >> 3, g = idx & 7;
        u16x8 v;
#pragma unroll
        for (int j = 0; j < 8; ++j) v[j] = t[g * 8 + j][c];
        *(u16x8*)(VT_g + ((long)(b * 512 + c0 + c) * VT_LD + k0 + g * 8)) = v;
    }
}

// ---------------------------------------------------------------------------
// MFMA flash attention in the 576-dim latent space (512 c + 64 rope).
// v9 = v8's lagged-PV schedule with the SPILL REMOVED:
//   v8 post-mortem: flash 363->414 with FETCH +34MB / WRITE +15MB at
//   unchanged algorithmic traffic = scratch-spill signature. Cause: per-wave
//   V self-staging forced vh[4] (16 VGPR) live ACROSS the S-phase peak ->
//   past the 256-reg file. Fix: restore v7's block-staged, DOUBLE-buffered
//   V (vh loaded after softmax, transient — v7's register profile), keep
//   the lagged PV + single barrier:
//   per iteration kt: stage K(kt+1) + V(kt) (DMA, drained by the one
//   end-of-tile barrier); S(kt) from K(kt) -> P/alpha/flag[kt&1];
//   then vh <- V[(kt-1)&1], rescale by alpha[(kt-1)&1], PV(kt-1).
//   Epilogue PV consumes the final tile. No mid-tile barrier, no mid-loop
//   lgkm wait. LDS: K dbuf 72K + V dbuf 64K + P dbuf 20K + misc 1.6K =
//   161,344 B <= 160 KiB; 1 block/CU (unchanged).
//
// grid (32 bh, 8 y); block 512 = 8 waves; q-tiles qt=15-y then y => exactly
// 68 key-tiles/block. Staging maps, softmax (log2-domain, defer-max THR=8,
// per-lane l partials), causal masks, c-split PV and guards byte-identical
// to verified v7 (PV side shifted to k0' = k0-32).
// ---------------------------------------------------------------------------
__global__ __launch_bounds__(512, 1) void flash_mfma(
    const unsigned short* __restrict__ qabs,  const unsigned short* __restrict__ qrope,
    const unsigned short* __restrict__ ckv,   const unsigned short* __restrict__ krope,
    const unsigned short* __restrict__ VT_g,  unsigned short* __restrict__ attn_out)
{
    __shared__ unsigned short K_lds[2][2304 * 8];       // 2 x 36 KB
    __shared__ unsigned short V_lds[2][2048 * 8];       // 2 x 32 KB
    __shared__ unsigned short P_lds[2][8][16 * 40];     // dbuf, +8 pad rows
    __shared__ __align__(16) float alpha_lds[2][8 * 16];
    __shared__ __align__(16) float inv_lds[8 * 16];
    __shared__ int flag_lds[2][8];

    const float scale2 = 0.10412195f;   // (1/sqrt(192)) * log2(e)
    const float THR    = 11.5416f;      // 8 * log2(e)
    const int tid = threadIdx.x;
    const int lane = tid & 63, w = tid >> 6;
    const int l15 = lane & 15, q4 = lane >> 4;
    const int bh = blockIdx.x;
    const int b = bh >> 4;

    const unsigned short* ckv_b  = ckv   + (long)b * S_LEN * 576;
    const unsigned short* krop_b = krope + (long)b * S_LEN * 64;
    const unsigned short* vt_b   = VT_g  + (long)b * 512 * VT_LD;

    // per-thread staging source offsets (bf16 elements), v7 mapping
    int koff[4], voff[4];
#pragma unroll
    for (int it = 0; it < 4; ++it) {
        const int idx = it * 512 + tid;
        const int key = ((idx >> 6) & 1) * 16 + (idx & 15);
        const int g   = (idx >> 7) * 4 + ((idx >> 4) & 3);   // < 64
        koff[it] = key * 576 + g * 8;
        const int c   = (idx >> 6) * 16 + (idx & 15);
        voff[it] = c * VT_LD + ((idx >> 4) & 3) * 8;
    }
    const int hoff = (((tid >> 6) & 1) * 16 + (tid & 15)) * 64 +
                     ((tid >> 7) * 4 + ((tid >> 4) & 3)) * 8;   // krope (tid<256)

#pragma unroll 1
    for (int half = 0; half < 2; ++half) {
        const int qt = half ? blockIdx.y : 15 - blockIdx.y;
        const int q0 = qt * 128;

        // Q fragments: rows q0 + w*16 + l15, dims kb*32 + q4*8 (+j)
        s16x8 qf[18];
        {
            const unsigned short* qa = qabs + ((long)bh * S_LEN + q0 + w * 16 + l15) * 512 + q4 * 8;
#pragma unroll
            for (int kb = 0; kb < 16; ++kb) qf[kb] = *(const s16x8*)(qa + kb * 32);
            const unsigned short* qr = qrope + ((long)bh * S_LEN + q0 + w * 16 + l15) * 64 + q4 * 8;
            qf[16] = *(const s16x8*)(qr);
            qf[17] = *(const s16x8*)(qr + 32);
        }

        // O[rb][cb]: 16 rows (rowblock rb) x 16 c (c = w*64 + cb*16 + l15)
        f32x4 O[32];
#pragma unroll
        for (int i = 0; i < 32; ++i) O[i] = (f32x4){0.f, 0.f, 0.f, 0.f};
        float m_i[4] = {-INFINITY, -INFINITY, -INFINITY, -INFINITY};
        float l_i[4] = {0.f, 0.f, 0.f, 0.f};

        const int nkt = 4 * qt + 4;
        unsigned short *Kc = K_lds[0], *Kn = K_lds[1];

        // ---- prologue: stage K tile 0 ----
        {
#pragma unroll
            for (int it = 0; it < 4; ++it)
                gl2lds16(ckv_b + koff[it], (char*)Kc + ((it * 512 + w * 64) << 4));
            if (tid < 256)
                gl2lds16(krop_b + hoff, (char*)Kc + ((2048 + w * 64) << 4));
        }
        __syncthreads();  // drain tile-0 K DMA

// rescale-O + PV for tile with key-base K0P from P/alpha/flag buffer PRV,
// V frags in VH (wave's own c-slice). rb-activity guard matches S at K0P.
#define PV_TILE(PRV, K0P, VH)                                                              \
        {                                                                                  \
            const int* fp = flag_lds[PRV];                                                 \
            const int anyf = fp[0] | fp[1] | fp[2] | fp[3] | fp[4] | fp[5] | fp[6] | fp[7];\
            if (anyf) {                                                                    \
                _Pragma("unroll")                                                          \
                for (int rb = 0; rb < 8; ++rb) {                                           \
                    if ((K0P) <= q0 + rb * 16 + 15) {                                      \
                        f32x4 alr = *(const f32x4*)&alpha_lds[PRV][rb * 16 + q4 * 4];      \
                        _Pragma("unroll")                                                  \
                        for (int cb = 0; cb < 4; ++cb)                                     \
                            _Pragma("unroll")                                              \
                            for (int r = 0; r < 4; ++r)                                    \
                                O[rb * 4 + cb][r] *= alr[r];                               \
                    }                                                                      \
                }                                                                          \
            }                                                                              \
            _Pragma("unroll")                                                              \
            for (int rb = 0; rb < 8; ++rb) {                                               \
                if ((K0P) <= q0 + rb * 16 + 15) {                                          \
                    s16x8 pa = *(const s16x8*)&P_lds[PRV][rb][l15 * 40 + q4 * 8];          \
                    __builtin_amdgcn_s_setprio(1);                                         \
                    _Pragma("unroll")                                                      \
                    for (int cb = 0; cb < 4; ++cb)                                         \
                        O[rb * 4 + cb] = __builtin_amdgcn_mfma_f32_16x16x32_bf16(          \
                            pa, VH[cb], O[rb * 4 + cb], 0, 0, 0);                          \
                    __builtin_amdgcn_s_setprio(0);                                         \
                }                                                                          \
            }                                                                              \
        }

        for (int kt = 0; kt < nkt; ++kt) {
            const int k0 = kt * 32;
            const int cur = kt & 1, prv = cur ^ 1;
            const int k0p = k0 - 32;

            // ---- stage K tile kt+1 (lands under this tile's compute) ----
            if (kt + 1 < nkt) {
                const int kn = k0 + 32;
                const unsigned short* cs = ckv_b + (long)kn * 576;
#pragma unroll
                for (int it = 0; it < 4; ++it)
                    gl2lds16(cs + koff[it], (char*)Kn + ((it * 512 + w * 64) << 4));
                if (tid < 256)
                    gl2lds16(krop_b + (long)kn * 64 + hoff, (char*)Kn + ((2048 + w * 64) << 4));
            }
            // ---- stage V tile kt into V_lds[cur] (PV(kt) runs next iter) ----
            {
                const unsigned short* vs = vt_b + k0;
#pragma unroll
                for (int it = 0; it < 4; ++it)
                    gl2lds16(vs + voff[it], (char*)V_lds[cur] + ((it * 512 + w * 64) << 4));
            }

            // ---- S(kt) for MY 16 rows (skip if fully masked) ----
            if (k0 <= q0 + (w << 4) + 15) {
                f32x4 s0 = {0.f, 0.f, 0.f, 0.f}, s1 = s0;
                __builtin_amdgcn_s_setprio(1);
#pragma unroll
                for (int kb = 0; kb < 18; ++kb) {
                    s16x8 k0f = *(const s16x8*)&Kc[((kb * 2 + 0) * 64 + lane) * 8];
                    s16x8 k1f = *(const s16x8*)&Kc[((kb * 2 + 1) * 64 + lane) * 8];
                    s0 = __builtin_amdgcn_mfma_f32_16x16x32_bf16(qf[kb], k0f, s0, 0, 0, 0);
                    s1 = __builtin_amdgcn_mfma_f32_16x16x32_bf16(qf[kb], k1f, s1, 0, 0, 0);
                }
                __builtin_amdgcn_s_setprio(0);
#pragma unroll
                for (int r = 0; r < 4; ++r) { s0[r] *= scale2; s1[r] *= scale2; }
                if (k0 + 31 > q0 + (w << 4)) {  // diagonal tiles: causal mask
#pragma unroll
                    for (int r = 0; r < 4; ++r) {
                        const int qg = q0 + w * 16 + q4 * 4 + r;
                        if (k0 + l15 > qg)      s0[r] = -INFINITY;
                        if (k0 + 16 + l15 > qg) s1[r] = -INFINITY;
                    }
                }

                // online softmax (log2 domain, defer-max)
                float mx[4];
#pragma unroll
                for (int r = 0; r < 4; ++r) {
                    float m = fmaxf(s0[r], s1[r]);
#pragma unroll
                    for (int off = 1; off < 16; off <<= 1) m = fmaxf(m, __shfl_xor(m, off, 64));
                    mx[r] = m;   // uniform within the 16-lane row group
                }
                bool need = false;
#pragma unroll
                for (int r = 0; r < 4; ++r) need = need || (mx[r] - m_i[r] > THR);
                const bool needw = __any(need);
                float al[4] = {1.f, 1.f, 1.f, 1.f};
                if (needw) {
#pragma unroll
                    for (int r = 0; r < 4; ++r) {
                        const float mn = fmaxf(m_i[r], mx[r]);
                        al[r] = exp2f(m_i[r] - mn);   // first tile: exp2(-inf)=0
                        m_i[r] = mn;
                        l_i[r] *= al[r];
                    }
                }
                if (l15 == 0)
                    *(f32x4*)&alpha_lds[cur][w * 16 + q4 * 4] = (f32x4){al[0], al[1], al[2], al[3]};
                if (lane == 0) flag_lds[cur][w] = needw ? 1 : 0;
#pragma unroll
                for (int r = 0; r < 4; ++r) {
                    const float p0 = exp2f(s0[r] - m_i[r]);
                    const float p1 = exp2f(s1[r] - m_i[r]);
                    l_i[r] += p0 + p1;   // per-lane partial; reduced in epilogue
                    P_lds[cur][w][(q4 * 4 + r) * 40 + l15]      = f2b(p0);
                    P_lds[cur][w][(q4 * 4 + r) * 40 + 16 + l15] = f2b(p1);
                }
            } else {
                if (lane == 0) flag_lds[cur][w] = 0;
            }

            // ---- PV(kt-1): P/alpha/flag + V from prv buffers (published by
            //      the previous barrier); vh transient (post-softmax regs) ----
            if (kt > 0) {
                s16x8 vh[4];
#pragma unroll
                for (int cb = 0; cb < 4; ++cb)
                    vh[cb] = *(const s16x8*)&V_lds[prv][((w * 4 + cb) * 64 + lane) * 8];
                PV_TILE(prv, k0p, vh)
            }

            // ---- ONE barrier per tile: drains K(kt+1)+V(kt) DMA, publishes
            //      P/alpha/flag(kt), protects buffer swap ----
            __syncthreads();
            unsigned short* t;
            t = Kc; Kc = Kn; Kn = t;
        }

        // ---- epilogue PV for the last tile ----
        {
            const int prv = (nkt - 1) & 1;
            const int k0p = (nkt - 1) * 32;
            s16x8 vh[4];
#pragma unroll
            for (int cb = 0; cb < 4; ++cb)
                vh[cb] = *(const s16x8*)&V_lds[prv][((w * 4 + cb) * 64 + lane) * 8];
            PV_TILE(prv, k0p, vh)
        }
#undef PV_TILE

        // ---- epilogue: per-row 1/l via LDS, O *= inv, c-split store ----
#pragma unroll
        for (int r = 0; r < 4; ++r) {
            float ls = l_i[r];
#pragma unroll
            for (int off = 1; off < 16; off <<= 1) ls += __shfl_xor(ls, off, 64);
            l_i[r] = 1.0f / ls;
        }
        if (l15 == 0)
            *(f32x4*)&inv_lds[w * 16 + q4 * 4] = (f32x4){l_i[0], l_i[1], l_i[2], l_i[3]};
        lds_barrier();
#pragma unroll
        for (int rb = 0; rb < 8; ++rb) {
            f32x4 ivr = *(const f32x4*)&inv_lds[rb * 16 + q4 * 4];
#pragma unroll
            for (int r = 0; r < 4; ++r) {
                const long rowbase = ((long)bh * S_LEN + q0 + rb * 16 + q4 * 4 + r) * 512;
#pragma unroll
                for (int cb = 0; cb < 4; ++cb)
                    attn_out[rowbase + w * 64 + cb * 16 + l15] = f2b(O[rb * 4 + cb][r] * ivr[r]);
            }
        }
        __syncthreads();  // P/alpha/V/inv reuse guard for next half
    }
}

// ---------------------------------------------------------------------------
extern "C" void kernel_launch(void* const* d_in, const int* in_sizes, int n_in,
                              void* d_out, int out_size, void* d_ws, size_t ws_size,
                              hipStream_t stream)
{
    (void)in_sizes; (void)n_in; (void)out_size; (void)ws_size;
    const float* hs_f       = (const float*)d_in[0];
    const int*   pos        = (const int*)d_in[1];
    // d_in[2] = attention_mask (causal, recomputed analytically) - unused
    const float* Wq_down_f  = (const float*)d_in[3];
    const float* q_ln_w_f   = (const float*)d_in[4];
    const float* Wq_up_f    = (const float*)d_in[5];
    const float* Wkv_down_f = (const float*)d_in[6];
    const float* Wkv_up_f   = (const float*)d_in[7];
    const float* Wo_f       = (const float*)d_in[8];
    float* out = (float*)d_out;

    // workspace layout (bf16 elements). out2 aliases q (dead after step 7).
    unsigned short* ws    = (unsigned short*)d_ws;
    unsigned short* ql    = ws;                        // 4096*1536
    unsigned short* q     = ql    + 4096L * 1536;      // 4096*3072
    unsigned short* out2  = q;                         // 4096*2048 (alias)
    unsigned short* ckv   = q     + 4096L * 3072;      // 4096*576
    unsigned short* krope = ckv   + 4096L * 576;       // 4096*64
    unsigned short* qrope = krope + 4096L * 64;        // 32*2048*64
    unsigned short* qabsT = qrope + 32L * 2048 * 64;   // 16*512*128
    unsigned short* qabs  = qabsT + 16L * 512 * 128;   // 32*2048*512
    unsigned short* attno = qabs  + 32L * 2048 * 512;  // 32*2048*512
    unsigned short* hs    = attno + 32L * 2048 * 512;  // 4096*2048
    unsigned short* Wqd   = hs    + 4096L * 2048;      // 1536*2048
    unsigned short* qlnw  = Wqd   + 1536L * 2048;      // 1536
    unsigned short* Wqu   = qlnw  + 1536;              // 3072*1536
    unsigned short* Wkvd  = Wqu   + 3072L * 1536;      // 576*2048
    unsigned short* Wkvu  = Wkvd  + 576L * 2048;       // 16*256*512
    unsigned short* Wob   = Wkvu  + 16L * 256 * 512;   // 2048*2048
    unsigned short* VTg   = Wob   + 2048L * 2048;      // 2*512*VT_LD (padded)

    // 0) fp32 -> bf16 input conversion
    f32_to_bf16<<<4096, 256, 0, stream>>>(hs_f,       hs,   4096L * 2048);
    f32_to_bf16<<<3072, 256, 0, stream>>>(Wq_down_f,  Wqd,  1536L * 2048);
    f32_to_bf16<<<2,    256, 0, stream>>>(q_ln_w_f,   qlnw, 1536L);
    f32_to_bf16<<<4096, 256, 0, stream>>>(Wq_up_f,    Wqu,  3072L * 1536);
    f32_to_bf16<<<1152, 256, 0, stream>>>(Wkv_down_f, Wkvd, 576L * 2048);
    f32_to_bf16<<<2048, 256, 0, stream>>>(Wkv_up_f,   Wkvu, 16L * 256 * 512);
    f32_to_bf16<<<4096, 256, 0, stream>>>(Wo_f,       Wob,  2048L * 2048);

    // 1) ql = hs @ Wq_down^T   (4096x1536, K=2048)
    gemm128<unsigned short><<<dim3(32, 12, 1), 256, 0, stream>>>(hs, Wqd, ql,
        2048, 2048, 2048, 1536, 1536, 0, 0, 0, 0, 0, 0);
    // 2) RMSNorm(ql)
    rmsnorm_k<<<4096, 256, 0, stream>>>(ql, qlnw);
    // 3) q = ql @ Wq_up^T      (4096x3072, K=1536)
    gemm128<unsigned short><<<dim3(32, 24, 1), 256, 0, stream>>>(ql, Wqu, q,
        1536, 1536, 1536, 3072, 3072, 0, 0, 0, 0, 0, 0);
    // 4) ckv = hs @ Wkv_down^T (2048x576, K=2048); Nlim guards last tile
    gemm128<unsigned short><<<dim3(32, 5, 1), 256, 0, stream>>>(hs, Wkvd, ckv,
        2048, 2048, 2048, 576, 576, 0, 0, 0, 0, 0, 0);
    // 5) RoPE on q (per head) and k
    rope_k<<<4096, 512, 0, stream>>>(q, ckv, pos, qrope, krope);
    // 5b) VT_g[b][c][key] = ckv[b][key][c], row stride VT_LD
    transpose_ckv<<<dim3(32, 8, 2), 256, 0, stream>>>(ckv, VTg);
    // 6) transpose q_absorb -> (h, c, n)
    transpose_qabsorb<<<4096, 256, 0, stream>>>(Wkvu, qabsT);
    // 7) q_abs[b,h] = q_nope[b,h] @ q_absorbT[h]^T  (2048x512, K=128), batched 32
    gemm128<unsigned short><<<dim3(16, 4, 32), 256, 0, stream>>>(q, qabsT, qabs,
        128, 3072, 128, 512, 512,
        2048L * 3072, 192, 0, 512L * 128, 16L * 2048 * 512, 2048L * 512);
    // 8) MFMA flash attention -> attn_out (B,NH,S,512): lagged PV, single
    //    barrier/tile, K+V+P double-buffered; 161.3 KB LDS, 1 block/CU
    flash_mfma<<<dim3(32, 8, 1), 512, 0, stream>>>(qabs, qrope, ckv, krope, VTg, attno);
    // 9) out2 = attn_out @ out_absorb^T per head (2048x128, K=512), batched 32
    gemm128<unsigned short><<<dim3(16, 1, 32), 256, 0, stream>>>(attno, Wkvu + 128L * 512, out2,
        512, 512, 512, 2048, 128,
        16L * 2048 * 512, 2048L * 512, 0, 256L * 512, 2048L * 2048, 128);
    // 10) out = out2 @ Wo^T    (4096x2048, K=2048), fp32 output
    gemm128<float><<<dim3(32, 16, 1), 256, 0, stream>>>(out2, Wob, out,
        2048, 2048, 2048, 2048, 2048, 0, 0, 0, 0, 0, 0);
}

// Round 10
// 753.447 us; speedup vs baseline: 1.1135x; 1.0431x over previous
//
#include <hip/hip_runtime.h>
#include <cstdint>

// Problem constants (MicroCortexMLA): B=2, S=2048, H=2048, NH=16,
// NOPE=128, ROPE=64, VD=128, QLORA=1536, KVLORA=512, theta=1e6, eps=1e-6
// Harness dtypes: fp32 inputs (converted to bf16 in ws), int32 pos, fp32 out.
// v10 = v7 flash (verified 363us; v8/v9 lagged-PV experiments were neutral ->
// reverted) + non-flash fixes: prestaged-K gemm for step 7 (K=128: 1 barrier
// instead of 8) + all 7 fp32->bf16 conversions merged into one launch.
#define S_LEN 2048
#define NH_N  16
#define VT_LD 2080  // padded row stride for VT_g

typedef short s16x8 __attribute__((ext_vector_type(8)));
typedef unsigned short u16x8 __attribute__((ext_vector_type(8)));
typedef float f32x4 __attribute__((ext_vector_type(4)));

__device__ __forceinline__ float b2f(unsigned short u) {
    return __uint_as_float(((uint32_t)u) << 16);
}
// round-to-nearest-even f32 -> bf16
__device__ __forceinline__ unsigned short f2b(float f) {
    uint32_t x = __float_as_uint(f);
    x += 0x7fffu + ((x >> 16) & 1u);
    return (unsigned short)(x >> 16);
}

__device__ __forceinline__ void cstore(unsigned short* p, float v) { *p = f2b(v); }
__device__ __forceinline__ void cstore(float* p, float v) { *p = v; }

// async global->LDS DMA, 16B per lane. LDS dst is wave-uniform base; HW adds
// lane*16. Tracked by vmcnt; __syncthreads() drains it.
__device__ __forceinline__ void gl2lds16(const void* g, void* l) {
    __builtin_amdgcn_global_load_lds(
        (const __attribute__((address_space(1))) unsigned int*)g,
        (__attribute__((address_space(3))) unsigned int*)l, 16, 0, 0);
}

// lgkm-only barrier: makes LDS writes visible block-wide WITHOUT draining
// vmcnt (in-flight global_load_lds prefetch stays outstanding).
__device__ __forceinline__ void lds_barrier() {
    asm volatile("s_waitcnt lgkmcnt(0)" ::: "memory");
    __builtin_amdgcn_s_barrier();
    __builtin_amdgcn_sched_barrier(0);
}

// ---------------------------------------------------------------------------
// Merged fp32 -> bf16 conversion: all 7 arrays, one launch, grid-stride per
// segment. All n % 4 == 0 (qlnw n=1536 -> 384 float4s).
// ---------------------------------------------------------------------------
__device__ __forceinline__ void conv_seg(const float* __restrict__ in,
                                         unsigned short* __restrict__ out,
                                         long n, long i0, long stride)
{
    const long nv = n >> 2;
    for (long i = i0; i < nv; i += stride) {
        float4 v = ((const float4*)in)[i];
        ushort4 o;
        o.x = f2b(v.x); o.y = f2b(v.y); o.z = f2b(v.z); o.w = f2b(v.w);
        ((ushort4*)out)[i] = o;
    }
}

__global__ __launch_bounds__(256) void f32_to_bf16_all(
    const float* __restrict__ s0, unsigned short* __restrict__ d0, long n0,
    const float* __restrict__ s1, unsigned short* __restrict__ d1, long n1,
    const float* __restrict__ s2, unsigned short* __restrict__ d2, long n2,
    const float* __restrict__ s3, unsigned short* __restrict__ d3, long n3,
    const float* __restrict__ s4, unsigned short* __restrict__ d4, long n4,
    const float* __restrict__ s5, unsigned short* __restrict__ d5, long n5,
    const float* __restrict__ s6, unsigned short* __restrict__ d6, long n6)
{
    const long i0 = (long)blockIdx.x * blockDim.x + threadIdx.x;
    const long st = (long)gridDim.x * blockDim.x;
    conv_seg(s0, d0, n0, i0, st);
    conv_seg(s1, d1, n1, i0, st);
    conv_seg(s2, d2, n2, i0, st);
    conv_seg(s3, d3, n3, i0, st);
    conv_seg(s4, d4, n4, i0, st);
    conv_seg(s5, d5, n5, i0, st);
    conv_seg(s6, d6, n6, i0, st);
}

// ---------------------------------------------------------------------------
// C = A @ B^T, m97-style: 128x128 block tile, BK=32, LDS staged via
// global_load_lds (16B/lane), 2-barrier K-loop. block 256 = 4 waves; wave w
// computes 64x64 at (w>>1, w&1) quadrant = 4x4 MFMA accs.
// LDS granule swizzle: position gp of row holds source granule
// gp ^ ((row ^ (row>>2)) & 3)  -> frag ds_read_b128 2-way max (free).
// Stores guarded by col < Nlim (B rows beyond N read adjacent ws, harmless).
// Batched over blockIdx.z = b*16+h. M%128==0, K%32==0, 16B alignment.
// ---------------------------------------------------------------------------
template <typename CT>
__global__ __launch_bounds__(256) void gemm128(
    const unsigned short* __restrict__ A, const unsigned short* __restrict__ B,
    CT* __restrict__ C,
    int K, int lda, int ldb, int ldc, int Nlim,
    long sAb, long sAh, long sBb, long sBh, long sCb, long sCh)
{
    __shared__ unsigned short Alds[128 * 32];
    __shared__ unsigned short Blds[128 * 32];
    const int z = blockIdx.z, b = z >> 4, h = z & 15;
    A += (long)b * sAb + (long)h * sAh;
    B += (long)b * sBb + (long)h * sBh;
    C += (long)b * sCb + (long)h * sCh;
    const int tid = threadIdx.x;
    const int lane = tid & 63, w = tid >> 6;
    const int l15 = lane & 15, q4 = lane >> 4;
    const int m0 = blockIdx.x * 128, n0 = blockIdx.y * 128;
    const int wm = (w >> 1) * 64, wn = (w & 1) * 64;

    // per-thread staging constants (2 granules per tile)
    int srow[2], sgc[2];
#pragma unroll
    for (int it = 0; it < 2; ++it) {
        const int g = it * 256 + tid;
        const int row = g >> 2, gp = g & 3;
        srow[it] = row;
        sgc[it] = gp ^ ((row ^ (row >> 2)) & 3);
    }
    // per-thread frag read offsets
    int aoff[4], boff[4];
#pragma unroll
    for (int i = 0; i < 4; ++i) {
        const int ra = wm + i * 16 + l15;
        aoff[i] = ra * 32 + (q4 ^ ((ra ^ (ra >> 2)) & 3)) * 8;
        const int rb = wn + i * 16 + l15;
        boff[i] = rb * 32 + (q4 ^ ((rb ^ (rb >> 2)) & 3)) * 8;
    }

    f32x4 acc[4][4];
#pragma unroll
    for (int i = 0; i < 4; ++i)
#pragma unroll
        for (int j = 0; j < 4; ++j) acc[i][j] = (f32x4){0.f, 0.f, 0.f, 0.f};

    for (int k0 = 0; k0 < K; k0 += 32) {
        __syncthreads();  // previous iter's frag reads done
#pragma unroll
        for (int it = 0; it < 2; ++it) {
            gl2lds16(A + (long)(m0 + srow[it]) * lda + k0 + sgc[it] * 8,
                     (char*)Alds + ((it * 256 + w * 64) << 4));
            gl2lds16(B + (long)(n0 + srow[it]) * ldb + k0 + sgc[it] * 8,
                     (char*)Blds + ((it * 256 + w * 64) << 4));
        }
        __syncthreads();  // drain DMA
        s16x8 af[4], bf[4];
#pragma unroll
        for (int i = 0; i < 4; ++i) {
            af[i] = *(const s16x8*)(Alds + aoff[i]);
            bf[i] = *(const s16x8*)(Blds + boff[i]);
        }
#pragma unroll
        for (int i = 0; i < 4; ++i)
#pragma unroll
            for (int j = 0; j < 4; ++j)
                acc[i][j] = __builtin_amdgcn_mfma_f32_16x16x32_bf16(af[i], bf[j], acc[i][j], 0, 0, 0);
    }

#pragma unroll
    for (int i = 0; i < 4; ++i) {
        const int row0 = m0 + wm + i * 16 + q4 * 4;
#pragma unroll
        for (int j = 0; j < 4; ++j) {
            const int col = n0 + wn + j * 16 + l15;
            if (col < Nlim) {
#pragma unroll
                for (int r = 0; r < 4; ++r)
                    cstore(&C[(long)(row0 + r) * ldc + col], acc[i][j][r]);
            }
        }
    }
}

// ---------------------------------------------------------------------------
// gemm128k128: gemm128 specialized for K == 128 (step 7). All 4 K-panels of
// A and B are staged upfront (64 KB LDS, 16 DMA/thread), ONE barrier, then
// 64 MFMAs/wave straight through — the BK=32 loop never fills its pipeline
// at 4 iterations (8 barrier drains for 4 compute bursts). Same swizzle /
// frag offsets / C-write as gemm128, panel-indexed.
// ---------------------------------------------------------------------------
__global__ __launch_bounds__(256) void gemm128k128(
    const unsigned short* __restrict__ A, const unsigned short* __restrict__ B,
    unsigned short* __restrict__ C,
    int lda, int ldb, int ldc, int Nlim,
    long sAb, long sAh, long sBb, long sBh, long sCb, long sCh)
{
    __shared__ unsigned short Alds[4][128 * 32];
    __shared__ unsigned short Blds[4][128 * 32];
    const int z = blockIdx.z, b = z >> 4, h = z & 15;
    A += (long)b * sAb + (long)h * sAh;
    B += (long)b * sBb + (long)h * sBh;
    C += (long)b * sCb + (long)h * sCh;
    const int tid = threadIdx.x;
    const int lane = tid & 63, w = tid >> 6;
    const int l15 = lane & 15, q4 = lane >> 4;
    const int m0 = blockIdx.x * 128, n0 = blockIdx.y * 128;
    const int wm = (w >> 1) * 64, wn = (w & 1) * 64;

    int srow[2], sgc[2];
#pragma unroll
    for (int it = 0; it < 2; ++it) {
        const int g = it * 256 + tid;
        const int row = g >> 2, gp = g & 3;
        srow[it] = row;
        sgc[it] = gp ^ ((row ^ (row >> 2)) & 3);
    }
    int aoff[4], boff[4];
#pragma unroll
    for (int i = 0; i < 4; ++i) {
        const int ra = wm + i * 16 + l15;
        aoff[i] = ra * 32 + (q4 ^ ((ra ^ (ra >> 2)) & 3)) * 8;
        const int rb = wn + i * 16 + l15;
        boff[i] = rb * 32 + (q4 ^ ((rb ^ (rb >> 2)) & 3)) * 8;
    }

    // stage all 4 K-panels of A and B
#pragma unroll
    for (int p = 0; p < 4; ++p) {
#pragma unroll
        for (int it = 0; it < 2; ++it) {
            gl2lds16(A + (long)(m0 + srow[it]) * lda + p * 32 + sgc[it] * 8,
                     (char*)Alds[p] + ((it * 256 + w * 64) << 4));
            gl2lds16(B + (long)(n0 + srow[it]) * ldb + p * 32 + sgc[it] * 8,
                     (char*)Blds[p] + ((it * 256 + w * 64) << 4));
        }
    }
    __syncthreads();  // drain DMA (the only barrier)

    f32x4 acc[4][4];
#pragma unroll
    for (int i = 0; i < 4; ++i)
#pragma unroll
        for (int j = 0; j < 4; ++j) acc[i][j] = (f32x4){0.f, 0.f, 0.f, 0.f};

#pragma unroll
    for (int p = 0; p < 4; ++p) {
        s16x8 af[4], bf[4];
#pragma unroll
        for (int i = 0; i < 4; ++i) {
            af[i] = *(const s16x8*)(Alds[p] + aoff[i]);
            bf[i] = *(const s16x8*)(Blds[p] + boff[i]);
        }
#pragma unroll
        for (int i = 0; i < 4; ++i)
#pragma unroll
            for (int j = 0; j < 4; ++j)
                acc[i][j] = __builtin_amdgcn_mfma_f32_16x16x32_bf16(af[i], bf[j], acc[i][j], 0, 0, 0);
    }

#pragma unroll
    for (int i = 0; i < 4; ++i) {
        const int row0 = m0 + wm + i * 16 + q4 * 4;
#pragma unroll
        for (int j = 0; j < 4; ++j) {
            const int col = n0 + wn + j * 16 + l15;
            if (col < Nlim) {
#pragma unroll
                for (int r = 0; r < 4; ++r)
                    cstore(&C[(long)(row0 + r) * ldc + col], acc[i][j][r]);
            }
        }
    }
}

// ---------------------------------------------------------------------------
// In-place RMSNorm over rows of 1536, one block per row.
// ---------------------------------------------------------------------------
__global__ __launch_bounds__(256) void rmsnorm_k(unsigned short* __restrict__ ql,
                                                 const unsigned short* __restrict__ w)
{
    const long base = (long)blockIdx.x * 1536;
    const int tid = threadIdx.x;
    float v[6];
    float ss = 0.f;
#pragma unroll
    for (int i = 0; i < 6; ++i) {
        v[i] = b2f(ql[base + tid + i * 256]);
        ss += v[i] * v[i];
    }
#pragma unroll
    for (int off = 32; off; off >>= 1) ss += __shfl_xor(ss, off, 64);
    __shared__ float red[4];
    if ((tid & 63) == 0) red[tid >> 6] = ss;
    __syncthreads();
    const float tot = red[0] + red[1] + red[2] + red[3];
    const float r = rsqrtf(tot * (1.0f / 1536.0f) + 1e-6f);
#pragma unroll
    for (int i = 0; i < 6; ++i) {
        const int idx = tid + i * 256;
        ql[base + idx] = f2b(v[i] * r * b2f(w[idx]));
    }
}

// ---------------------------------------------------------------------------
// RoPE for q (per head) and k (reference's permuted layout, consistent q/k).
// ---------------------------------------------------------------------------
__global__ __launch_bounds__(512) void rope_k(
    const unsigned short* __restrict__ q, const unsigned short* __restrict__ ckv,
    const int* __restrict__ pos_ids,
    unsigned short* __restrict__ q_rope, unsigned short* __restrict__ krope)
{
    const int bs = blockIdx.x;
    const int b = bs >> 11, s = bs & 2047;
    const int t = threadIdx.x;
    const int j = t & 31, h = t >> 5;
    const float pos = (float)pos_ids[bs];
    const float invf = __expf(-(float)j * 0.4317347f);  // ln(1e6)/32
    float sn, cs;
    sincosf(pos * invf, &sn, &cs);
    const unsigned short* x = q + (long)bs * 3072 + h * 192 + 128;
    const float x0 = b2f(x[2 * j]), x1 = b2f(x[2 * j + 1]);
    const long ob = ((long)(b * NH_N + h) * S_LEN + s) * 64;
    q_rope[ob + j]      = f2b(x0 * cs - x1 * sn);
    q_rope[ob + 32 + j] = f2b(x1 * cs + x0 * sn);
    if (h == 0) {
        const unsigned short* y = ckv + (long)bs * 576 + 512;
        const float y0 = b2f(y[2 * j]), y1 = b2f(y[2 * j + 1]);
        const long ob2 = (long)bs * 64;
        krope[ob2 + j]      = f2b(y0 * cs - y1 * sn);
        krope[ob2 + 32 + j] = f2b(y1 * cs + y0 * sn);
    }
}

// qT[h][c][n] = Wkv_up[(h*256+n)*512 + c]
__global__ __launch_bounds__(256) void transpose_qabsorb(
    const unsigned short* __restrict__ Wkv_up, unsigned short* __restrict__ qT)
{
    const int idx = blockIdx.x * 256 + threadIdx.x;
    const int n = idx & 127;
    const int c = (idx >> 7) & 511;
    const int h = idx >> 16;
    qT[idx] = Wkv_up[((long)(h * 256 + n)) * 512 + c];
}

// ---------------------------------------------------------------------------
// VT_g[b][c][key] = ckv[b][key][c]  (c < 512) — V^T for the PV MFMA B-frags.
// Tiled 64x64 transpose through LDS. grid (32 keyblk, 8 cblk, 2 b).
// ---------------------------------------------------------------------------
__global__ __launch_bounds__(256) void transpose_ckv(
    const unsigned short* __restrict__ ckv, unsigned short* __restrict__ VT_g)
{
    __shared__ unsigned short t[64][72];  // +8 pad
    const int k0 = blockIdx.x * 64, c0 = blockIdx.y * 64, b = blockIdx.z;
    const int tid = threadIdx.x;
#pragma unroll
    for (int it = 0; it < 2; ++it) {
        int idx = tid + it * 256;  // 512 tasks: 64 rows x 8 granules
        int row = idx >> 3, g = idx & 7;
        *(s16x8*)&t[row][g * 8] =
            *(const s16x8*)(ckv + ((long)(b * S_LEN + k0 + row) * 576 + c0 + g * 8));
    }
    __syncthreads();
#pragma unroll
    for (int it = 0; it < 2; ++it) {
        int idx = tid + it * 256;  // 512 tasks: 64 c x 8 key-granules
        int c = idx >> 3, g = idx & 7;
        u16x8 v;
#pragma unroll
        for (int j = 0; j < 8; ++j) v[j] = t[g * 8 + j][c];
        *(u16x8*)(VT_g + ((long)(b * 512 + c0 + c) * VT_LD + k0 + g * 8)) = v;
    }
}

// ---------------------------------------------------------------------------
// MFMA flash attention in the 576-dim latent space (512 c + 64 rope).
// v7 structure (verified 363us): K+V LDS dbuf, 8 waves/128-row q-tile, with
//  1) c-split PV: wave w owns c-slice [w*64,w*64+64) for ALL 128 rows.
//     V-frag reads 32->4/wave (hoisted in regs); P A-frags 8/wave read
//     cross-wave from P_lds. Mid-tile LGKM-ONLY barrier (raw s_barrier;
//     vmcnt prefetch untouched). Past-diagonal rowblocks skipped identically
//     on write & read side.
//  2) softmax: log2-domain exp2, defer-max (THR=8; rescale only when a
//     wave's tile-max grows >THR, flag via LDS), per-lane l partials
//     reduced once in the epilogue.
// (v8/v9 lagged-PV single-barrier variants measured neutral-to-worse;
//  reverted per falsifier.)
//
// grid (32 bh, 8 y); block 512 = 8 waves; q-tiles qt=15-y then y => exactly
// 68 key-tiles/block (256 blocks = 1/CU at 150 KB LDS).
// K/VT staged via global_load_lds in CONSUMPTION ORDER (slot = frag*64+lane
// -> zero-conflict ds_read_b128).
// ---------------------------------------------------------------------------
__global__ __launch_bounds__(512, 1) void flash_mfma(
    const unsigned short* __restrict__ qabs,  const unsigned short* __restrict__ qrope,
    const unsigned short* __restrict__ ckv,   const unsigned short* __restrict__ krope,
    const unsigned short* __restrict__ VT_g,  unsigned short* __restrict__ attn_out)
{
    __shared__ unsigned short K_lds[2][2304 * 8];   // 2 x 36 KB
    __shared__ unsigned short VT_lds[2][2048 * 8];  // 2 x 32 KB
    __shared__ unsigned short P_lds[8][16 * 40];    // P, +8 pad rows
    __shared__ float alpha_lds[8 * 16];             // per-row rescale factors
    __shared__ float inv_lds[8 * 16];               // per-row 1/l (epilogue)
    __shared__ int   flag_lds[8];                   // per-wave rescale flag

    const float scale2 = 0.10412195f;   // (1/sqrt(192)) * log2(e)
    const float THR    = 11.5416f;      // 8 * log2(e)
    const int tid = threadIdx.x;
    const int lane = tid & 63, w = tid >> 6;
    const int l15 = lane & 15, q4 = lane >> 4;
    const int bh = blockIdx.x;
    const int b = bh >> 4;

    const unsigned short* ckv_b  = ckv   + (long)b * S_LEN * 576;
    const unsigned short* krop_b = krope + (long)b * S_LEN * 64;
    const unsigned short* vt_b   = VT_g  + (long)b * 512 * VT_LD;

    // per-thread staging source offsets (bf16 elements)
    int koff[4], voff[4];
#pragma unroll
    for (int it = 0; it < 4; ++it) {
        const int idx = it * 512 + tid;
        const int key = ((idx >> 6) & 1) * 16 + (idx & 15);
        const int g   = (idx >> 7) * 4 + ((idx >> 4) & 3);   // < 64
        koff[it] = key * 576 + g * 8;
        const int c   = (idx >> 6) * 16 + (idx & 15);
        voff[it] = c * VT_LD + ((idx >> 4) & 3) * 8;
    }
    const int hoff = (((tid >> 6) & 1) * 16 + (tid & 15)) * 64 +
                     ((tid >> 7) * 4 + ((tid >> 4) & 3)) * 8;   // krope (tid<256)

#pragma unroll 1
    for (int half = 0; half < 2; ++half) {
        const int qt = half ? blockIdx.y : 15 - blockIdx.y;
        const int q0 = qt * 128;

        // Q fragments: rows q0 + w*16 + l15, dims kb*32 + q4*8 (+j)
        s16x8 qf[18];
        {
            const unsigned short* qa = qabs + ((long)bh * S_LEN + q0 + w * 16 + l15) * 512 + q4 * 8;
#pragma unroll
            for (int kb = 0; kb < 16; ++kb) qf[kb] = *(const s16x8*)(qa + kb * 32);
            const unsigned short* qr = qrope + ((long)bh * S_LEN + q0 + w * 16 + l15) * 64 + q4 * 8;
            qf[16] = *(const s16x8*)(qr);
            qf[17] = *(const s16x8*)(qr + 32);
        }

        // O[rb][cb]: 16 rows (rowblock rb) x 16 c (c = w*64 + cb*16 + l15)
        f32x4 O[32];
#pragma unroll
        for (int i = 0; i < 32; ++i) O[i] = (f32x4){0.f, 0.f, 0.f, 0.f};
        float m_i[4] = {-INFINITY, -INFINITY, -INFINITY, -INFINITY};
        float l_i[4] = {0.f, 0.f, 0.f, 0.f};

        const int nkt = 4 * qt + 4;
        unsigned short *Kc = K_lds[0], *Kn = K_lds[1];
        unsigned short *Vc = VT_lds[0], *Vn = VT_lds[1];

        // ---- prologue: stage tile 0 ----
        {
#pragma unroll
            for (int it = 0; it < 4; ++it)
                gl2lds16(ckv_b + koff[it], (char*)Kc + ((it * 512 + w * 64) << 4));
            if (tid < 256)
                gl2lds16(krop_b + hoff, (char*)Kc + ((2048 + w * 64) << 4));
#pragma unroll
            for (int it = 0; it < 4; ++it)
                gl2lds16(vt_b + voff[it], (char*)Vc + ((it * 512 + w * 64) << 4));
        }
        __syncthreads();  // drain tile-0 DMA

        for (int kt = 0; kt < nkt; ++kt) {
            const int k0 = kt * 32;

            // ---- stage tile kt+1 (lands under this tile's compute) ----
            if (kt + 1 < nkt) {
                const int kn = k0 + 32;
                const unsigned short* cs = ckv_b + (long)kn * 576;
#pragma unroll
                for (int it = 0; it < 4; ++it)
                    gl2lds16(cs + koff[it], (char*)Kn + ((it * 512 + w * 64) << 4));
                if (tid < 256)
                    gl2lds16(krop_b + (long)kn * 64 + hoff, (char*)Kn + ((2048 + w * 64) << 4));
                const unsigned short* vs = vt_b + kn;
#pragma unroll
                for (int it = 0; it < 4; ++it)
                    gl2lds16(vs + voff[it], (char*)Vn + ((it * 512 + w * 64) << 4));
            }

            // ---- S-phase + softmax for MY 16 rows (skip if fully masked) ----
            if (k0 <= q0 + (w << 4) + 15) {
                f32x4 s0 = {0.f, 0.f, 0.f, 0.f}, s1 = s0;
                __builtin_amdgcn_s_setprio(1);
#pragma unroll
                for (int kb = 0; kb < 18; ++kb) {
                    s16x8 k0f = *(const s16x8*)&Kc[((kb * 2 + 0) * 64 + lane) * 8];
                    s16x8 k1f = *(const s16x8*)&Kc[((kb * 2 + 1) * 64 + lane) * 8];
                    s0 = __builtin_amdgcn_mfma_f32_16x16x32_bf16(qf[kb], k0f, s0, 0, 0, 0);
                    s1 = __builtin_amdgcn_mfma_f32_16x16x32_bf16(qf[kb], k1f, s1, 0, 0, 0);
                }
                __builtin_amdgcn_s_setprio(0);
#pragma unroll
                for (int r = 0; r < 4; ++r) { s0[r] *= scale2; s1[r] *= scale2; }
                if (k0 + 31 > q0 + (w << 4)) {  // diagonal tiles: causal mask
#pragma unroll
                    for (int r = 0; r < 4; ++r) {
                        const int qg = q0 + w * 16 + q4 * 4 + r;
                        if (k0 + l15 > qg)      s0[r] = -INFINITY;
                        if (k0 + 16 + l15 > qg) s1[r] = -INFINITY;
                    }
                }

                // online softmax (log2 domain, defer-max)
                float mx[4];
#pragma unroll
                for (int r = 0; r < 4; ++r) {
                    float m = fmaxf(s0[r], s1[r]);
#pragma unroll
                    for (int off = 1; off < 16; off <<= 1) m = fmaxf(m, __shfl_xor(m, off, 64));
                    mx[r] = m;   // uniform within the 16-lane row group
                }
                bool need = false;
#pragma unroll
                for (int r = 0; r < 4; ++r) need = need || (mx[r] - m_i[r] > THR);
                const bool needw = __any(need);
                float al[4] = {1.f, 1.f, 1.f, 1.f};
                if (needw) {
#pragma unroll
                    for (int r = 0; r < 4; ++r) {
                        const float mn = fmaxf(m_i[r], mx[r]);
                        al[r] = exp2f(m_i[r] - mn);   // first tile: exp2(-inf)=0
                        m_i[r] = mn;
                        l_i[r] *= al[r];
                    }
                }
                if (l15 == 0)
                    *(f32x4*)&alpha_lds[w * 16 + q4 * 4] = (f32x4){al[0], al[1], al[2], al[3]};
                if (lane == 0) flag_lds[w] = needw ? 1 : 0;
#pragma unroll
                for (int r = 0; r < 4; ++r) {
                    const float p0 = exp2f(s0[r] - m_i[r]);
                    const float p1 = exp2f(s1[r] - m_i[r]);
                    l_i[r] += p0 + p1;   // per-lane partial; reduced in epilogue
                    P_lds[w][(q4 * 4 + r) * 40 + l15]      = f2b(p0);
                    P_lds[w][(q4 * 4 + r) * 40 + 16 + l15] = f2b(p1);
                }
            } else {
                if (lane == 0) flag_lds[w] = 0;
            }

            // ---- mid-tile barrier: P/alpha/flag visible; vmcnt NOT drained ----
            lds_barrier();

            // ---- O-rescale (c-split): only if some wave rescaled ----
            {
                int4 f0 = *(const int4*)&flag_lds[0];
                int4 f1 = *(const int4*)&flag_lds[4];
                if (f0.x | f0.y | f0.z | f0.w | f1.x | f1.y | f1.z | f1.w) {
#pragma unroll
                    for (int rb = 0; rb < 8; ++rb) {
                        if (k0 <= q0 + rb * 16 + 15) {   // active rowblocks only
                            f32x4 alr = *(const f32x4*)&alpha_lds[rb * 16 + q4 * 4];
#pragma unroll
                            for (int cb = 0; cb < 4; ++cb)
#pragma unroll
                                for (int r = 0; r < 4; ++r)
                                    O[rb * 4 + cb][r] *= alr[r];
                        }
                    }
                }
            }

            // ---- PV (c-split): V hoisted (4 frags), P A-frag per rowblock ----
            {
                s16x8 vh[4];
#pragma unroll
                for (int cb = 0; cb < 4; ++cb)
                    vh[cb] = *(const s16x8*)&Vc[((w * 4 + cb) * 64 + lane) * 8];
#pragma unroll
                for (int rb = 0; rb < 8; ++rb) {
                    if (k0 <= q0 + rb * 16 + 15) {
                        s16x8 pa = *(const s16x8*)&P_lds[rb][l15 * 40 + q4 * 8];
                        __builtin_amdgcn_s_setprio(1);
#pragma unroll
                        for (int cb = 0; cb < 4; ++cb)
                            O[rb * 4 + cb] = __builtin_amdgcn_mfma_f32_16x16x32_bf16(pa, vh[cb], O[rb * 4 + cb], 0, 0, 0);
                        __builtin_amdgcn_s_setprio(0);
                    }
                }
            }

            // ---- end-of-tile barrier: drains kt+1 DMA (landed under compute)
            //      + protects P/alpha overwrite and buffer swap ----
            __syncthreads();
            unsigned short* t;
            t = Kc; Kc = Kn; Kn = t;
            t = Vc; Vc = Vn; Vn = t;
        }

        // ---- epilogue: per-row 1/l via LDS, O *= inv, c-split store ----
#pragma unroll
        for (int r = 0; r < 4; ++r) {
            float ls = l_i[r];
#pragma unroll
            for (int off = 1; off < 16; off <<= 1) ls += __shfl_xor(ls, off, 64);
            l_i[r] = 1.0f / ls;
        }
        if (l15 == 0)
            *(f32x4*)&inv_lds[w * 16 + q4 * 4] = (f32x4){l_i[0], l_i[1], l_i[2], l_i[3]};
        lds_barrier();
#pragma unroll
        for (int rb = 0; rb < 8; ++rb) {
            f32x4 ivr = *(const f32x4*)&inv_lds[rb * 16 + q4 * 4];
#pragma unroll
            for (int r = 0; r < 4; ++r) {
                const long rowbase = ((long)bh * S_LEN + q0 + rb * 16 + q4 * 4 + r) * 512;
#pragma unroll
                for (int cb = 0; cb < 4; ++cb)
                    attn_out[rowbase + w * 64 + cb * 16 + l15] = f2b(O[rb * 4 + cb][r] * ivr[r]);
            }
        }
        __syncthreads();  // inv_lds/P_lds reuse guard for next half
    }
}

// ---------------------------------------------------------------------------
extern "C" void kernel_launch(void* const* d_in, const int* in_sizes, int n_in,
                              void* d_out, int out_size, void* d_ws, size_t ws_size,
                              hipStream_t stream)
{
    (void)in_sizes; (void)n_in; (void)out_size; (void)ws_size;
    const float* hs_f       = (const float*)d_in[0];
    const int*   pos        = (const int*)d_in[1];
    // d_in[2] = attention_mask (causal, recomputed analytically) - unused
    const float* Wq_down_f  = (const float*)d_in[3];
    const float* q_ln_w_f   = (const float*)d_in[4];
    const float* Wq_up_f    = (const float*)d_in[5];
    const float* Wkv_down_f = (const float*)d_in[6];
    const float* Wkv_up_f   = (const float*)d_in[7];
    const float* Wo_f       = (const float*)d_in[8];
    float* out = (float*)d_out;

    // workspace layout (bf16 elements). out2 aliases q (dead after step 7).
    unsigned short* ws    = (unsigned short*)d_ws;
    unsigned short* ql    = ws;                        // 4096*1536
    unsigned short* q     = ql    + 4096L * 1536;      // 4096*3072
    unsigned short* out2  = q;                         // 4096*2048 (alias)
    unsigned short* ckv   = q     + 4096L * 3072;      // 4096*576
    unsigned short* krope = ckv   + 4096L * 576;       // 4096*64
    unsigned short* qrope = krope + 4096L * 64;        // 32*2048*64
    unsigned short* qabsT = qrope + 32L * 2048 * 64;   // 16*512*128
    unsigned short* qabs  = qabsT + 16L * 512 * 128;   // 32*2048*512
    unsigned short* attno = qabs  + 32L * 2048 * 512;  // 32*2048*512
    unsigned short* hs    = attno + 32L * 2048 * 512;  // 4096*2048
    unsigned short* Wqd   = hs    + 4096L * 2048;      // 1536*2048
    unsigned short* qlnw  = Wqd   + 1536L * 2048;      // 1536
    unsigned short* Wqu   = qlnw  + 1536;              // 3072*1536
    unsigned short* Wkvd  = Wqu   + 3072L * 1536;      // 576*2048
    unsigned short* Wkvu  = Wkvd  + 576L * 2048;       // 16*256*512
    unsigned short* Wob   = Wkvu  + 16L * 256 * 512;   // 2048*2048
    unsigned short* VTg   = Wob   + 2048L * 2048;      // 2*512*VT_LD (padded)

    // 0) fp32 -> bf16 input conversion — ONE launch for all 7 arrays
    f32_to_bf16_all<<<2048, 256, 0, stream>>>(
        hs_f,       hs,   4096L * 2048,
        Wq_down_f,  Wqd,  1536L * 2048,
        q_ln_w_f,   qlnw, 1536L,
        Wq_up_f,    Wqu,  3072L * 1536,
        Wkv_down_f, Wkvd, 576L * 2048,
        Wkv_up_f,   Wkvu, 16L * 256 * 512,
        Wo_f,       Wob,  2048L * 2048);

    // 1) ql = hs @ Wq_down^T   (4096x1536, K=2048)
    gemm128<unsigned short><<<dim3(32, 12, 1), 256, 0, stream>>>(hs, Wqd, ql,
        2048, 2048, 2048, 1536, 1536, 0, 0, 0, 0, 0, 0);
    // 2) RMSNorm(ql)
    rmsnorm_k<<<4096, 256, 0, stream>>>(ql, qlnw);
    // 3) q = ql @ Wq_up^T      (4096x3072, K=1536)
    gemm128<unsigned short><<<dim3(32, 24, 1), 256, 0, stream>>>(ql, Wqu, q,
        1536, 1536, 1536, 3072, 3072, 0, 0, 0, 0, 0, 0);
    // 4) ckv = hs @ Wkv_down^T (2048x576, K=2048); Nlim guards last tile
    gemm128<unsigned short><<<dim3(32, 5, 1), 256, 0, stream>>>(hs, Wkvd, ckv,
        2048, 2048, 2048, 576, 576, 0, 0, 0, 0, 0, 0);
    // 5) RoPE on q (per head) and k
    rope_k<<<4096, 512, 0, stream>>>(q, ckv, pos, qrope, krope);
    // 5b) VT_g[b][c][key] = ckv[b][key][c], row stride VT_LD
    transpose_ckv<<<dim3(32, 8, 2), 256, 0, stream>>>(ckv, VTg);
    // 6) transpose q_absorb -> (h, c, n)
    transpose_qabsorb<<<4096, 256, 0, stream>>>(Wkvu, qabsT);
    // 7) q_abs[b,h] = q_nope[b,h] @ q_absorbT[h]^T  (2048x512, K=128),
    //    batched 32 — prestaged-K kernel (1 barrier instead of 8)
    gemm128k128<<<dim3(16, 4, 32), 256, 0, stream>>>(q, qabsT, qabs,
        3072, 128, 512, 512,
        2048L * 3072, 192, 0, 512L * 128, 16L * 2048 * 512, 2048L * 512);
    // 8) MFMA flash attention -> attn_out (B,NH,S,512): v7 structure
    flash_mfma<<<dim3(32, 8, 1), 512, 0, stream>>>(qabs, qrope, ckv, krope, VTg, attno);
    // 9) out2 = attn_out @ out_absorb^T per head (2048x128, K=512), batched 32
    gemm128<unsigned short><<<dim3(16, 1, 32), 256, 0, stream>>>(attno, Wkvu + 128L * 512, out2,
        512, 512, 512, 2048, 128,
        16L * 2048 * 512, 2048L * 512, 0, 256L * 512, 2048L * 2048, 128);
    // 10) out = out2 @ Wo^T    (4096x2048, K=2048), fp32 output
    gemm128<float><<<dim3(32, 16, 1), 256, 0, stream>>>(out2, Wob, out,
        2048, 2048, 2048, 2048, 2048, 0, 0, 0, 0, 0, 0);
}